// Round 10
// baseline (236.333 us; speedup 1.0000x reference)
//
#include <hip/hip_runtime.h>

#define N_NODES 50000
#define N_EDGES 800000
#define IN_DIM  128
#define HID_DIM 256
#define OUT_DIM 128
#define BUCKET_CAP 64    // in-degree ~ Poisson(16); P(deg>64) ~ 2e-18 over 50k nodes
#define NCOARSE 196      // ceil(50000/256) coarse bins of 256 dst nodes
#define CHUNK 4000       // edges per binning block
#define NBLK1 200        // 200 * 4000 = 800000
#define SEGCAP 64        // per-(block,bin) capacity: Poisson(20.4) + 9.6 sigma
#define HLD 264          // LDS row stride (ushorts) for H tile: 256 + 8 pad
#define GROWS 64         // rows per gemm12 block

typedef __attribute__((ext_vector_type(8))) short short8;
typedef __attribute__((ext_vector_type(4))) float f32x4;

// ---- bf16 helpers (RNE) ----
__device__ inline ushort f2b(float f) {
    union { float f; unsigned u; } v; v.f = f;
    return (ushort)((v.u + 0x7FFFu + ((v.u >> 16) & 1u)) >> 16);
}
__device__ inline float b2f(ushort h) {
    union { unsigned u; float f; } v; v.u = ((unsigned)h) << 16;
    return v.f;
}
__device__ inline float2 u2f2(unsigned u) {
    float2 r; r.x = b2f((ushort)(u & 0xFFFFu)); r.y = b2f((ushort)(u >> 16)); return r;
}
__device__ inline unsigned f2u2(float a, float b) {
    return (unsigned)f2b(a) | ((unsigned)f2b(b) << 16);
}
__device__ inline void fma4h(float2* acc, uint2 u, float n) {
    float2 v0 = u2f2(u.x), v1 = u2f2(u.y);
    acc[0].x += v0.x * n; acc[0].y += v0.y * n;
    acc[1].x += v1.x * n; acc[1].y += v1.y * n;
}

// ---------------- prep: conv_x || conv_w || edge binning, one kernel ----------------

__global__ __launch_bounds__(256) void prep_kernel(const float* __restrict__ x,
                                                   const float* __restrict__ W1,
                                                   const float* __restrict__ W2,
                                                   const int* __restrict__ src,
                                                   const int* __restrict__ dst,
                                                   ushort* __restrict__ xb,
                                                   ushort* __restrict__ w1t,
                                                   ushort* __restrict__ w2t,
                                                   int* __restrict__ bcnt,
                                                   int* __restrict__ binbuf) {
    __shared__ int vals[CHUNK];           // 16 KB: (src<<8)|(dst&255)
    __shared__ ushort lpos[CHUNK];        // 8 KB
    __shared__ unsigned char lbin[CHUNK]; // 4 KB
    __shared__ int hist[NCOARSE];
    const int b = blockIdx.x;
    const int t = threadIdx.x;
    if (b < 6250) {
        int i = b * 256 + t;               // over N*128/4 float4s
        float4 v = ((const float4*)x)[i];
        ushort4 o; o.x = f2b(v.x); o.y = f2b(v.y); o.z = f2b(v.z); o.w = f2b(v.w);
        ((ushort4*)xb)[i] = o;
    } else if (b < 6506) {
        int i = (b - 6250) * 256 + t;      // 65536 total
        if (i < 32768) {
            int n = i >> 7, k = i & 127;
            w1t[i] = f2b(W1[k * HID_DIM + n]);
        } else {
            int j = i - 32768;
            int n = j >> 8, k = j & 255;
            w2t[j] = f2b(W2[k * OUT_DIM + n]);
        }
    } else {
        const int blk = b - 6506;
        const int e0 = blk * CHUNK;
        for (int i = t; i < NCOARSE; i += 256) hist[i] = 0;
        __syncthreads();
        for (int i = t; i < CHUNK; i += 256) {
            int s = src[e0 + i], d = dst[e0 + i];
            int bin = d >> 8;
            vals[i] = (s << 8) | (d & 255);
            lbin[i] = (unsigned char)bin;
            lpos[i] = (ushort)atomicAdd(&hist[bin], 1);
        }
        __syncthreads();
        for (int i = t; i < NCOARSE; i += 256) {
            int h = hist[i]; if (h > SEGCAP) h = SEGCAP;
            bcnt[i * NBLK1 + blk] = h;
        }
        for (int i = t; i < CHUNK; i += 256) {
            int bin = lbin[i];
            int p = lpos[i];
            if (p < SEGCAP) binbuf[((size_t)bin * NBLK1 + blk) * SEGCAP + p] = vals[i];
        }
    }
}

// ---------------- binpass2: one block per coarse bin (256 nodes) ----------------

__global__ __launch_bounds__(256) void binpass2_kernel(const int* __restrict__ bcnt,
                                                       const int* __restrict__ binbuf,
                                                       int* __restrict__ cnt,
                                                       float* __restrict__ dinv,
                                                       int* __restrict__ bucket) {
    __shared__ int lcnt[256];
    __shared__ int lm[NBLK1];
    __shared__ int lbuck[256 * BUCKET_CAP];   // 64 KB
    const int bin = blockIdx.x;
    const int t = threadIdx.x;
    lcnt[t] = 0;
    if (t < NBLK1) lm[t] = bcnt[bin * NBLK1 + t];
    __syncthreads();
    const int* bb = binbuf + (size_t)bin * NBLK1 * SEGCAP;
    for (int f = t; f < NBLK1 * SEGCAP; f += 256) {
        int blk = f >> 6;        // SEGCAP = 64
        int sl = f & 63;
        if (sl < lm[blk]) {
            int v = bb[f];
            int dl = v & 255;
            int pos = atomicAdd(&lcnt[dl], 1);
            if (pos < BUCKET_CAP) lbuck[dl * BUCKET_CAP + pos] = v >> 8;
        }
    }
    __syncthreads();
    const int node0 = bin * 256;
    int node = node0 + t;
    if (node < N_NODES) {
        int c = lcnt[t] > BUCKET_CAP ? BUCKET_CAP : lcnt[t];
        cnt[node] = c;
        dinv[node] = rsqrtf((float)c + 1.0f);
    }
    int nvalid = N_NODES - node0; if (nvalid > 256) nvalid = 256;
    if (nvalid <= 0) return;
    int total4 = (nvalid * BUCKET_CAP) >> 2;
    int4* d4 = (int4*)(bucket + (size_t)node0 * BUCKET_CAP);
    const int4* s4 = (const int4*)lbuck;
    for (int j = t; j < total4; j += 256) d4[j] = s4[j];
}

// ---------------- gather0: aggx = Ahat * x (bf16 in/out, fp32 acc) ----------------
// Feature-half split with XCD-aware mapping: half = (blk&7)>>2 so (with round-robin
// workgroup dispatch) half 0 lives on XCDs 0-3, half 1 on XCDs 4-7 -> each XCD's
// scattered working set is 6.4MB instead of 12.8MB. 25000 blocks, wave = (node,half);
// 16 lanes per edge x dwordx2, 4 edge-groups, branch-free padding.

__global__ __launch_bounds__(256) void gather0_kernel(const int* __restrict__ cnt,
                                                      const int* __restrict__ bucket,
                                                      const float* __restrict__ dinv,
                                                      const ushort* __restrict__ xb,
                                                      ushort* __restrict__ aggxb) {
    const int b = blockIdx.x;
    const int wv = threadIdx.x >> 6;
    const int lane = threadIdx.x & 63;
    const int half = (b & 7) >> 2;
    const int node = ((b >> 3) * 4 + (b & 3)) * 4 + wv;
    const int grp = lane >> 4, sub = lane & 15;
    const int n = cnt[node];
    const float dd = dinv[node];
    int sv = 0; float nv = 0.f;
    if (lane < n) { sv = bucket[node * BUCKET_CAP + lane]; nv = dinv[sv] * dd; }

    const ushort* base = xb + half * 64;   // column offset (64 features = 128B)
    float2 acc[2];
    if (grp == 0) {   // self term, group 0 only
        uint2 su = ((const uint2*)(base + (size_t)node * IN_DIM))[sub];
        float sd = dd * dd;
        acc[0] = u2f2(su.x); acc[1] = u2f2(su.y);
        acc[0].x *= sd; acc[0].y *= sd; acc[1].x *= sd; acc[1].y *= sd;
    } else {
        acc[0] = {0.f, 0.f}; acc[1] = {0.f, 0.f};
    }

    const int nr = (n + 15) & ~15;
    for (int i = 0; i < nr; i += 16) {
        int s0 = __shfl(sv, i + grp),      s1 = __shfl(sv, i + 4 + grp);
        int s2 = __shfl(sv, i + 8 + grp),  s3 = __shfl(sv, i + 12 + grp);
        float n0 = __shfl(nv, i + grp),     n1 = __shfl(nv, i + 4 + grp);
        float n2 = __shfl(nv, i + 8 + grp), n3 = __shfl(nv, i + 12 + grp);
        uint2 u0 = ((const uint2*)(base + (size_t)s0 * IN_DIM))[sub];
        uint2 u1 = ((const uint2*)(base + (size_t)s1 * IN_DIM))[sub];
        uint2 u2 = ((const uint2*)(base + (size_t)s2 * IN_DIM))[sub];
        uint2 u3 = ((const uint2*)(base + (size_t)s3 * IN_DIM))[sub];
        fma4h(acc, u0, n0); fma4h(acc, u1, n1); fma4h(acc, u2, n2); fma4h(acc, u3, n3);
    }
#pragma unroll
    for (int j = 0; j < 2; ++j) {
        acc[j].x += __shfl_down(acc[j].x, 32); acc[j].y += __shfl_down(acc[j].y, 32);
        acc[j].x += __shfl_down(acc[j].x, 16); acc[j].y += __shfl_down(acc[j].y, 16);
    }
    if (lane < 16) {
        uint2 o = {f2u2(acc[0].x, acc[0].y), f2u2(acc[1].x, acc[1].y)};
        ((uint2*)(aggxb + (size_t)node * IN_DIM + half * 64))[sub] = o;
    }
}

// ---------------- gemm12 (MFMA, fused): h2b = (relu(aggx@W1 + b1)) @ W2 ----------------
// Block = 64 rows; B-frags hoisted to registers, reused over 4 row-subtiles.

__global__ __launch_bounds__(256, 2) void gemm12_mfma(const ushort* __restrict__ aggxb,
                                                      const ushort* __restrict__ w1t,
                                                      const float* __restrict__ b1,
                                                      const ushort* __restrict__ w2t,
                                                      ushort* __restrict__ h2b) {
    __shared__ ushort Hs[GROWS * HLD];   // 33 KB
    const int row0 = blockIdx.x * GROWS;
    const int wv = threadIdx.x >> 6;
    const int lane = threadIdx.x & 63;
    const int l15 = lane & 15, q = lane >> 4;

    // ---- phase 1: H = relu(aggx @ W1 + b1) -> LDS ----
    short8 bf1[16];
#pragma unroll
    for (int kb = 0; kb < 4; ++kb)
#pragma unroll
        for (int t = 0; t < 4; ++t) {
            int col = wv * 64 + t * 16 + l15;
            bf1[kb * 4 + t] = *(const short8*)(w1t + (size_t)col * IN_DIM + kb * 32 + q * 8);
        }
    short8 af[4][4];
#pragma unroll
    for (int sub = 0; sub < 4; ++sub) {
        int ar = row0 + sub * 16 + l15;
        if (ar >= N_NODES) ar = N_NODES - 1;
        const ushort* ab = aggxb + (size_t)ar * IN_DIM + q * 8;
#pragma unroll
        for (int kb = 0; kb < 4; ++kb) af[sub][kb] = *(const short8*)(ab + kb * 32);
    }
    f32x4 acc1[4][4] = {};
#pragma unroll
    for (int sub = 0; sub < 4; ++sub)
#pragma unroll
        for (int kb = 0; kb < 4; ++kb)
#pragma unroll
            for (int t = 0; t < 4; ++t)
                acc1[sub][t] = __builtin_amdgcn_mfma_f32_16x16x32_bf16(
                    af[sub][kb], bf1[kb * 4 + t], acc1[sub][t], 0, 0, 0);
#pragma unroll
    for (int t = 0; t < 4; ++t) {
        int col = wv * 64 + t * 16 + l15;
        float bias = b1[col];
#pragma unroll
        for (int sub = 0; sub < 4; ++sub)
#pragma unroll
            for (int r = 0; r < 4; ++r) {
                int row = sub * 16 + q * 4 + r;
                float v = acc1[sub][t][r] + bias;
                Hs[row * HLD + col] = f2b(v > 0.f ? v : 0.f);
            }
    }
    __syncthreads();

    // ---- phase 2: h2 = H @ W2 (A from LDS, B hoisted) ----
    short8 bf2[16];
#pragma unroll
    for (int kb = 0; kb < 8; ++kb)
#pragma unroll
        for (int t = 0; t < 2; ++t) {
            int col = wv * 32 + t * 16 + l15;
            bf2[kb * 2 + t] = *(const short8*)(w2t + (size_t)col * HID_DIM + kb * 32 + q * 8);
        }
    f32x4 acc2[4][2] = {};
#pragma unroll
    for (int sub = 0; sub < 4; ++sub) {
        const ushort* hb = Hs + (sub * 16 + l15) * HLD + q * 8;
#pragma unroll
        for (int kb = 0; kb < 8; ++kb) {
            short8 a = *(const short8*)(hb + kb * 32);
#pragma unroll
            for (int t = 0; t < 2; ++t)
                acc2[sub][t] = __builtin_amdgcn_mfma_f32_16x16x32_bf16(
                    a, bf2[kb * 2 + t], acc2[sub][t], 0, 0, 0);
        }
    }
#pragma unroll
    for (int sub = 0; sub < 4; ++sub)
#pragma unroll
        for (int t = 0; t < 2; ++t) {
            int col = wv * 32 + t * 16 + l15;
#pragma unroll
            for (int r = 0; r < 4; ++r) {
                int row = row0 + sub * 16 + q * 4 + r;
                if (row < N_NODES)
                    h2b[(size_t)row * OUT_DIM + col] = f2b(acc2[sub][t][r]);
            }
        }
}

// ---------------- gather2: out = Ahat * h2 + b2 (bf16 in, fp32 out) ----------------
// same half-split + XCD mapping as gather0

__global__ __launch_bounds__(256) void gather2_kernel(const int* __restrict__ cnt,
                                                      const int* __restrict__ bucket,
                                                      const float* __restrict__ dinv,
                                                      const ushort* __restrict__ h2b,
                                                      const float* __restrict__ b2,
                                                      float* __restrict__ out) {
    const int b = blockIdx.x;
    const int wv = threadIdx.x >> 6;
    const int lane = threadIdx.x & 63;
    const int half = (b & 7) >> 2;
    const int node = ((b >> 3) * 4 + (b & 3)) * 4 + wv;
    const int grp = lane >> 4, sub = lane & 15;
    const int n = cnt[node];
    const float dd = dinv[node];
    int sv = 0; float nv = 0.f;
    if (lane < n) { sv = bucket[node * BUCKET_CAP + lane]; nv = dinv[sv] * dd; }

    const ushort* base = h2b + half * 64;
    float2 acc[2];
    if (grp == 0) {
        uint2 su = ((const uint2*)(base + (size_t)node * OUT_DIM))[sub];
        float sd = dd * dd;
        acc[0] = u2f2(su.x); acc[1] = u2f2(su.y);
        acc[0].x *= sd; acc[0].y *= sd; acc[1].x *= sd; acc[1].y *= sd;
    } else {
        acc[0] = {0.f, 0.f}; acc[1] = {0.f, 0.f};
    }

    const int nr = (n + 15) & ~15;
    for (int i = 0; i < nr; i += 16) {
        int s0 = __shfl(sv, i + grp),      s1 = __shfl(sv, i + 4 + grp);
        int s2 = __shfl(sv, i + 8 + grp),  s3 = __shfl(sv, i + 12 + grp);
        float n0 = __shfl(nv, i + grp),     n1 = __shfl(nv, i + 4 + grp);
        float n2 = __shfl(nv, i + 8 + grp), n3 = __shfl(nv, i + 12 + grp);
        uint2 u0 = ((const uint2*)(base + (size_t)s0 * OUT_DIM))[sub];
        uint2 u1 = ((const uint2*)(base + (size_t)s1 * OUT_DIM))[sub];
        uint2 u2 = ((const uint2*)(base + (size_t)s2 * OUT_DIM))[sub];
        uint2 u3 = ((const uint2*)(base + (size_t)s3 * OUT_DIM))[sub];
        fma4h(acc, u0, n0); fma4h(acc, u1, n1); fma4h(acc, u2, n2); fma4h(acc, u3, n3);
    }
#pragma unroll
    for (int j = 0; j < 2; ++j) {
        acc[j].x += __shfl_down(acc[j].x, 32); acc[j].y += __shfl_down(acc[j].y, 32);
        acc[j].x += __shfl_down(acc[j].x, 16); acc[j].y += __shfl_down(acc[j].y, 16);
    }
    if (lane < 16) {
        float4 bb = ((const float4*)b2)[half * 16 + sub];
        float4 o = {acc[0].x + bb.x, acc[0].y + bb.y, acc[1].x + bb.z, acc[1].y + bb.w};
        ((float4*)(out + (size_t)node * OUT_DIM + half * 64))[sub] = o;
    }
}

extern "C" void kernel_launch(void* const* d_in, const int* in_sizes, int n_in,
                              void* d_out, int out_size, void* d_ws, size_t ws_size,
                              hipStream_t stream) {
    const float* x  = (const float*)d_in[0];
    const int*   ei = (const int*)d_in[1];
    const float* W1 = (const float*)d_in[2];
    const float* b1 = (const float*)d_in[3];
    const float* W2 = (const float*)d_in[4];
    const float* b2 = (const float*)d_in[5];
    float* out = (float*)d_out;

    const int* src = ei;             // edge_index[0]
    const int* dst = ei + N_EDGES;   // edge_index[1]

    // workspace layout (bytes):
    //  bcnt   : [0, 160000)                 int[196*200]
    //  cnt    : [160000, 360000)            int[50000]
    //  dinv   : [360000, 560000)            float[50000]
    //  bucket : [560000, 13360000)          int[50000*64]
    //  binbuf : [13360000, 23395200)        int[196*200*64]
    //  xb     : [23395200, 36195200)        bf16[50000*128]
    //  w1t    : [36195200, 36260736)        bf16[256*128]
    //  w2t    : [36260736, 36326272)        bf16[128*256]
    //  aggxb  : [36326272, 49126272)        bf16[50000*128]
    //  h2b    : [49126272, 61926272)        bf16[50000*128]
    char* ws = (char*)d_ws;
    int*    bcnt   = (int*)(ws);
    int*    cnt    = (int*)(ws + 160000);
    float*  dinv   = (float*)(ws + 360000);
    int*    bucket = (int*)(ws + 560000);
    int*    binbuf = (int*)(ws + 13360000);
    ushort* xb     = (ushort*)(ws + 23395200);
    ushort* w1t    = (ushort*)(ws + 36195200);
    ushort* w2t    = (ushort*)(ws + 36260736);
    ushort* aggxb  = (ushort*)(ws + 36326272);
    ushort* h2b    = (ushort*)(ws + 49126272);

    // prep (conv_x || conv_w || binning) -> bucket build
    prep_kernel<<<6706, 256, 0, stream>>>(x, W1, W2, src, dst, xb, w1t, w2t, bcnt, binbuf);
    binpass2_kernel<<<NCOARSE, 256, 0, stream>>>(bcnt, binbuf, cnt, dinv, bucket);

    // layer 1 aggregate (half-split, XCD-mapped), then fused transform L1+L2
    gather0_kernel<<<N_NODES / 2, 256, 0, stream>>>(cnt, bucket, dinv, xb, aggxb);
    gemm12_mfma<<<(N_NODES + GROWS - 1) / GROWS, 256, 0, stream>>>(aggxb, w1t, b1, w2t, h2b);

    // layer 2 aggregate (self-loop + b2 fused)
    gather2_kernel<<<N_NODES / 2, 256, 0, stream>>>(cnt, bucket, dinv, h2b, b2, out);
}

// Round 11
// 234.236 us; speedup vs baseline: 1.0090x; 1.0090x over previous
//
#include <hip/hip_runtime.h>

#define N_NODES 50000
#define N_EDGES 800000
#define IN_DIM  128
#define HID_DIM 256
#define OUT_DIM 128
#define BUCKET_CAP 64    // in-degree ~ Poisson(16); P(deg>64) ~ 2e-18 over 50k nodes
#define NCOARSE 196      // ceil(50000/256) coarse bins of 256 dst nodes
#define CHUNK 4000       // edges per binning block
#define NBLK1 200        // 200 * 4000 = 800000
#define SEGCAP 64        // per-(block,bin) capacity: Poisson(20.4) + 9.6 sigma
#define HLD 264          // LDS row stride (ushorts) for H tile: 256 + 8 pad
#define GROWS 64         // rows per gemm12 block

typedef __attribute__((ext_vector_type(8))) short short8;
typedef __attribute__((ext_vector_type(4))) float f32x4;

// ---- bf16 helpers (RNE) ----
__device__ inline ushort f2b(float f) {
    union { float f; unsigned u; } v; v.f = f;
    return (ushort)((v.u + 0x7FFFu + ((v.u >> 16) & 1u)) >> 16);
}
__device__ inline float b2f(ushort h) {
    union { unsigned u; float f; } v; v.u = ((unsigned)h) << 16;
    return v.f;
}
__device__ inline float2 u2f2(unsigned u) {
    float2 r; r.x = b2f((ushort)(u & 0xFFFFu)); r.y = b2f((ushort)(u >> 16)); return r;
}
__device__ inline unsigned f2u2(float a, float b) {
    return (unsigned)f2b(a) | ((unsigned)f2b(b) << 16);
}
__device__ inline void fma8(float2* acc, uint4 u, float n) {
    float2 v0 = u2f2(u.x), v1 = u2f2(u.y), v2 = u2f2(u.z), v3 = u2f2(u.w);
    acc[0].x += v0.x * n; acc[0].y += v0.y * n;
    acc[1].x += v1.x * n; acc[1].y += v1.y * n;
    acc[2].x += v2.x * n; acc[2].y += v2.y * n;
    acc[3].x += v3.x * n; acc[3].y += v3.y * n;
}

// ---------------- prep: conv_x || conv_w || edge binning, one kernel ----------------

__global__ __launch_bounds__(256) void prep_kernel(const float* __restrict__ x,
                                                   const float* __restrict__ W1,
                                                   const float* __restrict__ W2,
                                                   const int* __restrict__ src,
                                                   const int* __restrict__ dst,
                                                   ushort* __restrict__ xb,
                                                   ushort* __restrict__ w1t,
                                                   ushort* __restrict__ w2t,
                                                   int* __restrict__ bcnt,
                                                   int* __restrict__ binbuf) {
    __shared__ int vals[CHUNK];           // 16 KB: (src<<8)|(dst&255)
    __shared__ ushort lpos[CHUNK];        // 8 KB
    __shared__ unsigned char lbin[CHUNK]; // 4 KB
    __shared__ int hist[NCOARSE];
    const int b = blockIdx.x;
    const int t = threadIdx.x;
    if (b < 6250) {
        int i = b * 256 + t;               // over N*128/4 float4s
        float4 v = ((const float4*)x)[i];
        ushort4 o; o.x = f2b(v.x); o.y = f2b(v.y); o.z = f2b(v.z); o.w = f2b(v.w);
        ((ushort4*)xb)[i] = o;
    } else if (b < 6506) {
        int i = (b - 6250) * 256 + t;      // 65536 total
        if (i < 32768) {
            int n = i >> 7, k = i & 127;
            w1t[i] = f2b(W1[k * HID_DIM + n]);
        } else {
            int j = i - 32768;
            int n = j >> 8, k = j & 255;
            w2t[j] = f2b(W2[k * OUT_DIM + n]);
        }
    } else {
        const int blk = b - 6506;
        const int e0 = blk * CHUNK;
        for (int i = t; i < NCOARSE; i += 256) hist[i] = 0;
        __syncthreads();
        for (int i = t; i < CHUNK; i += 256) {
            int s = src[e0 + i], d = dst[e0 + i];
            int bin = d >> 8;
            vals[i] = (s << 8) | (d & 255);
            lbin[i] = (unsigned char)bin;
            lpos[i] = (ushort)atomicAdd(&hist[bin], 1);
        }
        __syncthreads();
        for (int i = t; i < NCOARSE; i += 256) {
            int h = hist[i]; if (h > SEGCAP) h = SEGCAP;
            bcnt[i * NBLK1 + blk] = h;
        }
        for (int i = t; i < CHUNK; i += 256) {
            int bin = lbin[i];
            int p = lpos[i];
            if (p < SEGCAP) binbuf[((size_t)bin * NBLK1 + blk) * SEGCAP + p] = vals[i];
        }
    }
}

// ---------------- binpass2: one block per coarse bin (256 nodes) ----------------

__global__ __launch_bounds__(256) void binpass2_kernel(const int* __restrict__ bcnt,
                                                       const int* __restrict__ binbuf,
                                                       int* __restrict__ cnt,
                                                       float* __restrict__ dinv,
                                                       int* __restrict__ bucket) {
    __shared__ int lcnt[256];
    __shared__ int lm[NBLK1];
    __shared__ int lbuck[256 * BUCKET_CAP];   // 64 KB
    const int bin = blockIdx.x;
    const int t = threadIdx.x;
    lcnt[t] = 0;
    if (t < NBLK1) lm[t] = bcnt[bin * NBLK1 + t];
    __syncthreads();
    const int* bb = binbuf + (size_t)bin * NBLK1 * SEGCAP;
    for (int f = t; f < NBLK1 * SEGCAP; f += 256) {
        int blk = f >> 6;        // SEGCAP = 64
        int sl = f & 63;
        if (sl < lm[blk]) {
            int v = bb[f];
            int dl = v & 255;
            int pos = atomicAdd(&lcnt[dl], 1);
            if (pos < BUCKET_CAP) lbuck[dl * BUCKET_CAP + pos] = v >> 8;
        }
    }
    __syncthreads();
    const int node0 = bin * 256;
    int node = node0 + t;
    if (node < N_NODES) {
        int c = lcnt[t] > BUCKET_CAP ? BUCKET_CAP : lcnt[t];
        cnt[node] = c;
        dinv[node] = rsqrtf((float)c + 1.0f);
    }
    int nvalid = N_NODES - node0; if (nvalid > 256) nvalid = 256;
    if (nvalid <= 0) return;
    int total4 = (nvalid * BUCKET_CAP) >> 2;
    int4* d4 = (int4*)(bucket + (size_t)node0 * BUCKET_CAP);
    const int4* s4 = (const int4*)lbuck;
    for (int j = t; j < total4; j += 256) d4[j] = s4[j];
}

// ---------------- gather0: aggx = Ahat * x (bf16 in/out, fp32 acc) ----------------
// Feature-half split (XCD-aware: half = (blk&7)>>2) with FULL-WIDTH loads:
// 8 lanes per edge x uint4 (16B) -> one wave instruction covers 8 edges x 128B = 1KB.
// 16 edge-slots/iter = 2 independent loads/lane. Also emits per-edge norms (half 0)
// so gather2 skips the scattered dinv reads.

__global__ __launch_bounds__(256) void gather0_kernel(const int* __restrict__ cnt,
                                                      const int* __restrict__ bucket,
                                                      const float* __restrict__ dinv,
                                                      const ushort* __restrict__ xb,
                                                      ushort* __restrict__ aggxb,
                                                      float* __restrict__ normbuf) {
    const int b = blockIdx.x;
    const int wv = threadIdx.x >> 6;
    const int lane = threadIdx.x & 63;
    const int half = (b & 7) >> 2;
    const int node = ((b >> 3) * 4 + (b & 3)) * 4 + wv;
    const int grp = lane >> 3, sub = lane & 7;   // 8 edges/iter-slot x 8 lanes x 16B
    const int n = cnt[node];
    const float dd = dinv[node];
    int sv = 0; float nv = 0.f;
    if (lane < n) { sv = bucket[node * BUCKET_CAP + lane]; nv = dinv[sv] * dd; }
    if (half == 0 && lane < n) normbuf[node * BUCKET_CAP + lane] = nv;

    const ushort* base = xb + half * 64;   // 64 features = 128B per half-row
    float2 acc[4];
    if (grp == 0) {   // self term, group 0 only
        uint4 su = ((const uint4*)(base + (size_t)node * IN_DIM))[sub];
        float sd = dd * dd;
        acc[0] = u2f2(su.x); acc[1] = u2f2(su.y); acc[2] = u2f2(su.z); acc[3] = u2f2(su.w);
#pragma unroll
        for (int j = 0; j < 4; ++j) { acc[j].x *= sd; acc[j].y *= sd; }
    } else {
#pragma unroll
        for (int j = 0; j < 4; ++j) acc[j] = {0.f, 0.f};
    }

    const int nr = (n + 15) & ~15;
    for (int i = 0; i < nr; i += 16) {
        int s0 = __shfl(sv, i + grp), s1 = __shfl(sv, i + 8 + grp);
        float n0 = __shfl(nv, i + grp), n1 = __shfl(nv, i + 8 + grp);
        uint4 u0 = ((const uint4*)(base + (size_t)s0 * IN_DIM))[sub];
        uint4 u1 = ((const uint4*)(base + (size_t)s1 * IN_DIM))[sub];
        fma8(acc, u0, n0); fma8(acc, u1, n1);
    }
    // reduce across 8 groups (stride 8 lanes)
#pragma unroll
    for (int j = 0; j < 4; ++j) {
        acc[j].x += __shfl_down(acc[j].x, 32); acc[j].y += __shfl_down(acc[j].y, 32);
        acc[j].x += __shfl_down(acc[j].x, 16); acc[j].y += __shfl_down(acc[j].y, 16);
        acc[j].x += __shfl_down(acc[j].x, 8);  acc[j].y += __shfl_down(acc[j].y, 8);
    }
    if (lane < 8) {
        uint4 o = {f2u2(acc[0].x, acc[0].y), f2u2(acc[1].x, acc[1].y),
                   f2u2(acc[2].x, acc[2].y), f2u2(acc[3].x, acc[3].y)};
        ((uint4*)(aggxb + (size_t)node * IN_DIM + half * 64))[sub] = o;
    }
}

// ---------------- gemm12 (MFMA, fused): h2b = (relu(aggx@W1 + b1)) @ W2 ----------------
// Block = 64 rows; B-frags hoisted to registers, reused over 4 row-subtiles.

__global__ __launch_bounds__(256, 2) void gemm12_mfma(const ushort* __restrict__ aggxb,
                                                      const ushort* __restrict__ w1t,
                                                      const float* __restrict__ b1,
                                                      const ushort* __restrict__ w2t,
                                                      ushort* __restrict__ h2b) {
    __shared__ ushort Hs[GROWS * HLD];   // 33 KB
    const int row0 = blockIdx.x * GROWS;
    const int wv = threadIdx.x >> 6;
    const int lane = threadIdx.x & 63;
    const int l15 = lane & 15, q = lane >> 4;

    // ---- phase 1: H = relu(aggx @ W1 + b1) -> LDS ----
    short8 bf1[16];
#pragma unroll
    for (int kb = 0; kb < 4; ++kb)
#pragma unroll
        for (int t = 0; t < 4; ++t) {
            int col = wv * 64 + t * 16 + l15;
            bf1[kb * 4 + t] = *(const short8*)(w1t + (size_t)col * IN_DIM + kb * 32 + q * 8);
        }
    short8 af[4][4];
#pragma unroll
    for (int sub = 0; sub < 4; ++sub) {
        int ar = row0 + sub * 16 + l15;
        if (ar >= N_NODES) ar = N_NODES - 1;
        const ushort* ab = aggxb + (size_t)ar * IN_DIM + q * 8;
#pragma unroll
        for (int kb = 0; kb < 4; ++kb) af[sub][kb] = *(const short8*)(ab + kb * 32);
    }
    f32x4 acc1[4][4] = {};
#pragma unroll
    for (int sub = 0; sub < 4; ++sub)
#pragma unroll
        for (int kb = 0; kb < 4; ++kb)
#pragma unroll
            for (int t = 0; t < 4; ++t)
                acc1[sub][t] = __builtin_amdgcn_mfma_f32_16x16x32_bf16(
                    af[sub][kb], bf1[kb * 4 + t], acc1[sub][t], 0, 0, 0);
#pragma unroll
    for (int t = 0; t < 4; ++t) {
        int col = wv * 64 + t * 16 + l15;
        float bias = b1[col];
#pragma unroll
        for (int sub = 0; sub < 4; ++sub)
#pragma unroll
            for (int r = 0; r < 4; ++r) {
                int row = sub * 16 + q * 4 + r;
                float v = acc1[sub][t][r] + bias;
                Hs[row * HLD + col] = f2b(v > 0.f ? v : 0.f);
            }
    }
    __syncthreads();

    // ---- phase 2: h2 = H @ W2 (A from LDS, B hoisted) ----
    short8 bf2[16];
#pragma unroll
    for (int kb = 0; kb < 8; ++kb)
#pragma unroll
        for (int t = 0; t < 2; ++t) {
            int col = wv * 32 + t * 16 + l15;
            bf2[kb * 2 + t] = *(const short8*)(w2t + (size_t)col * HID_DIM + kb * 32 + q * 8);
        }
    f32x4 acc2[4][2] = {};
#pragma unroll
    for (int sub = 0; sub < 4; ++sub) {
        const ushort* hb = Hs + (sub * 16 + l15) * HLD + q * 8;
#pragma unroll
        for (int kb = 0; kb < 8; ++kb) {
            short8 a = *(const short8*)(hb + kb * 32);
#pragma unroll
            for (int t = 0; t < 2; ++t)
                acc2[sub][t] = __builtin_amdgcn_mfma_f32_16x16x32_bf16(
                    a, bf2[kb * 2 + t], acc2[sub][t], 0, 0, 0);
        }
    }
#pragma unroll
    for (int sub = 0; sub < 4; ++sub)
#pragma unroll
        for (int t = 0; t < 2; ++t) {
            int col = wv * 32 + t * 16 + l15;
#pragma unroll
            for (int r = 0; r < 4; ++r) {
                int row = row0 + sub * 16 + q * 4 + r;
                if (row < N_NODES)
                    h2b[(size_t)row * OUT_DIM + col] = f2b(acc2[sub][t][r]);
            }
        }
}

// ---------------- gather2: out = Ahat * h2 + b2 (bf16 in, fp32 out) ----------------
// same half-split + 8-lane x uint4 structure; norms read coalesced from normbuf.

__global__ __launch_bounds__(256) void gather2_kernel(const int* __restrict__ cnt,
                                                      const int* __restrict__ bucket,
                                                      const float* __restrict__ dinv,
                                                      const float* __restrict__ normbuf,
                                                      const ushort* __restrict__ h2b,
                                                      const float* __restrict__ b2,
                                                      float* __restrict__ out) {
    const int b = blockIdx.x;
    const int wv = threadIdx.x >> 6;
    const int lane = threadIdx.x & 63;
    const int half = (b & 7) >> 2;
    const int node = ((b >> 3) * 4 + (b & 3)) * 4 + wv;
    const int grp = lane >> 3, sub = lane & 7;
    const int n = cnt[node];
    const float dd = dinv[node];
    int sv = 0; float nv = 0.f;
    if (lane < n) {
        sv = bucket[node * BUCKET_CAP + lane];
        nv = normbuf[node * BUCKET_CAP + lane];   // coalesced, no scattered dinv
    }

    const ushort* base = h2b + half * 64;
    float2 acc[4];
    if (grp == 0) {
        uint4 su = ((const uint4*)(base + (size_t)node * OUT_DIM))[sub];
        float sd = dd * dd;
        acc[0] = u2f2(su.x); acc[1] = u2f2(su.y); acc[2] = u2f2(su.z); acc[3] = u2f2(su.w);
#pragma unroll
        for (int j = 0; j < 4; ++j) { acc[j].x *= sd; acc[j].y *= sd; }
    } else {
#pragma unroll
        for (int j = 0; j < 4; ++j) acc[j] = {0.f, 0.f};
    }

    const int nr = (n + 15) & ~15;
    for (int i = 0; i < nr; i += 16) {
        int s0 = __shfl(sv, i + grp), s1 = __shfl(sv, i + 8 + grp);
        float n0 = __shfl(nv, i + grp), n1 = __shfl(nv, i + 8 + grp);
        uint4 u0 = ((const uint4*)(base + (size_t)s0 * OUT_DIM))[sub];
        uint4 u1 = ((const uint4*)(base + (size_t)s1 * OUT_DIM))[sub];
        fma8(acc, u0, n0); fma8(acc, u1, n1);
    }
#pragma unroll
    for (int j = 0; j < 4; ++j) {
        acc[j].x += __shfl_down(acc[j].x, 32); acc[j].y += __shfl_down(acc[j].y, 32);
        acc[j].x += __shfl_down(acc[j].x, 16); acc[j].y += __shfl_down(acc[j].y, 16);
        acc[j].x += __shfl_down(acc[j].x, 8);  acc[j].y += __shfl_down(acc[j].y, 8);
    }
    if (lane < 8) {
        const float4* bp = (const float4*)b2;
        float4 ba = bp[half * 16 + sub * 2], bb = bp[half * 16 + sub * 2 + 1];
        float4 o0 = {acc[0].x + ba.x, acc[0].y + ba.y, acc[1].x + ba.z, acc[1].y + ba.w};
        float4 o1 = {acc[2].x + bb.x, acc[2].y + bb.y, acc[3].x + bb.z, acc[3].y + bb.w};
        float4* op = (float4*)(out + (size_t)node * OUT_DIM + half * 64);
        op[sub * 2] = o0;
        op[sub * 2 + 1] = o1;
    }
}

extern "C" void kernel_launch(void* const* d_in, const int* in_sizes, int n_in,
                              void* d_out, int out_size, void* d_ws, size_t ws_size,
                              hipStream_t stream) {
    const float* x  = (const float*)d_in[0];
    const int*   ei = (const int*)d_in[1];
    const float* W1 = (const float*)d_in[2];
    const float* b1 = (const float*)d_in[3];
    const float* W2 = (const float*)d_in[4];
    const float* b2 = (const float*)d_in[5];
    float* out = (float*)d_out;

    const int* src = ei;             // edge_index[0]
    const int* dst = ei + N_EDGES;   // edge_index[1]

    // workspace layout (bytes):
    //  bcnt    : [0, 160000)                int[196*200]
    //  cnt     : [160000, 360000)           int[50000]
    //  dinv    : [360000, 560000)           float[50000]
    //  bucket  : [560000, 13360000)         int[50000*64]
    //  binbuf  : [13360000, 23395200)       int[196*200*64]
    //  xb      : [23395200, 36195200)       bf16[50000*128]
    //  w1t     : [36195200, 36260736)       bf16[256*128]
    //  w2t     : [36260736, 36326272)       bf16[128*256]
    //  aggxb   : [36326272, 49126272)       bf16[50000*128]
    //  h2b     : [49126272, 61926272)       bf16[50000*128]
    //  normbuf : [61926272, 74726272)       float[50000*64]
    char* ws = (char*)d_ws;
    int*    bcnt    = (int*)(ws);
    int*    cnt     = (int*)(ws + 160000);
    float*  dinv    = (float*)(ws + 360000);
    int*    bucket  = (int*)(ws + 560000);
    int*    binbuf  = (int*)(ws + 13360000);
    ushort* xb      = (ushort*)(ws + 23395200);
    ushort* w1t     = (ushort*)(ws + 36195200);
    ushort* w2t     = (ushort*)(ws + 36260736);
    ushort* aggxb   = (ushort*)(ws + 36326272);
    ushort* h2b     = (ushort*)(ws + 49126272);
    float*  normbuf = (float*)(ws + 61926272);

    // prep (conv_x || conv_w || binning) -> bucket build
    prep_kernel<<<6706, 256, 0, stream>>>(x, W1, W2, src, dst, xb, w1t, w2t, bcnt, binbuf);
    binpass2_kernel<<<NCOARSE, 256, 0, stream>>>(bcnt, binbuf, cnt, dinv, bucket);

    // layer 1 aggregate (half-split, full-width loads; emits normbuf), fused transform
    gather0_kernel<<<N_NODES / 2, 256, 0, stream>>>(cnt, bucket, dinv, xb, aggxb, normbuf);
    gemm12_mfma<<<(N_NODES + GROWS - 1) / GROWS, 256, 0, stream>>>(aggxb, w1t, b1, w2t, h2b);

    // layer 2 aggregate (norms from normbuf; self-loop + b2 fused)
    gather2_kernel<<<N_NODES / 2, 256, 0, stream>>>(cnt, bucket, dinv, normbuf, h2b, b2, out);
}